// Round 1
// baseline (760.293 us; speedup 1.0000x reference)
//
#include <hip/hip_runtime.h>

typedef float f32x4 __attribute__((ext_vector_type(4)));
typedef short s16x8 __attribute__((ext_vector_type(8)));
typedef unsigned short u16;
typedef u16 u16x4 __attribute__((ext_vector_type(4)));

#define SEQ 2048
#define BATCH 2
#define NH 16
#define DH 128
#define DM 2048
#define MROWS (BATCH * SEQ)  // 4096

__device__ __forceinline__ u16 f2bf(float f) {
  unsigned u = __float_as_uint(f);
  u += 0x7fffu + ((u >> 16) & 1u);
  return (u16)(u >> 16);
}
__device__ __forceinline__ float bf2f(u16 b) {
  return __uint_as_float(((unsigned)b) << 16);
}

__device__ __forceinline__ void gld_lds16(const void* g, void* l) {
  __builtin_amdgcn_global_load_lds(
      (const __attribute__((address_space(1))) unsigned int*)g,
      (__attribute__((address_space(3))) unsigned int*)l, 16, 0, 0);
}

// ---------------- cast f32 -> bf16 (vectorized float4 -> 4x bf16) ----------
__global__ __launch_bounds__(256) void cast_kernel(const float* __restrict__ in,
                                                   u16* __restrict__ out, int n4) {
  int i = blockIdx.x * 256 + threadIdx.x;
  if (i >= n4) return;
  float4 v = ((const float4*)in)[i];
  u16x4 o;
  o[0] = f2bf(v.x); o[1] = f2bf(v.y); o[2] = f2bf(v.z); o[3] = f2bf(v.w);
  ((u16x4*)out)[i] = o;
}

// ---------------- GEMM C[m][n] = sum_k A[m][k]*B[n][k]  (bt form) ----------
// 128x128 tile, BK=32, 4 waves (2x2 of 64x64), mfma 16x16x32 bf16.
template <bool F32OUT>
__global__ __launch_bounds__(256) void gemm_bt(const u16* __restrict__ A,
                                               const u16* __restrict__ B,
                                               void* __restrict__ Cv,
                                               int M, int N, int K) {
  __shared__ u16 As[128 * 32];
  __shared__ u16 Bs[128 * 32];
  const int tid = threadIdx.x;
  const int wave = tid >> 6;
  const int lane = tid & 63;
  const int r = lane & 15, g = lane >> 4;

  const int m0 = blockIdx.y * 128;
  const int n0 = blockIdx.x * 128;
  const int wm = (wave >> 1) * 64;
  const int wn = (wave & 1) * 64;

  f32x4 acc[4][4] = {};

  const int row0 = tid >> 2;          // 0..63
  const int col0 = (tid & 3) * 8;     // element col within BK
  const u16* ga0 = A + (long)(m0 + row0) * K + col0;
  const u16* ga1 = A + (long)(m0 + 64 + row0) * K + col0;
  const u16* gb0 = B + (long)(n0 + row0) * K + col0;
  const u16* gb1 = B + (long)(n0 + 64 + row0) * K + col0;

  u16* lA0 = &As[wave * 512];
  u16* lA1 = &As[2048 + wave * 512];
  u16* lB0 = &Bs[wave * 512];
  u16* lB1 = &Bs[2048 + wave * 512];

  for (int k0 = 0; k0 < K; k0 += 32) {
    gld_lds16(ga0 + k0, lA0);
    gld_lds16(ga1 + k0, lA1);
    gld_lds16(gb0 + k0, lB0);
    gld_lds16(gb1 + k0, lB1);
    __syncthreads();
    s16x8 af[4], bfr[4];
#pragma unroll
    for (int i = 0; i < 4; i++) {
      af[i]  = *(const s16x8*)&As[(wm + i * 16 + r) * 32 + g * 8];
      bfr[i] = *(const s16x8*)&Bs[(wn + i * 16 + r) * 32 + g * 8];
    }
#pragma unroll
    for (int i = 0; i < 4; i++)
#pragma unroll
      for (int j = 0; j < 4; j++)
        acc[i][j] = __builtin_amdgcn_mfma_f32_16x16x32_bf16(af[i], bfr[j], acc[i][j], 0, 0, 0);
    __syncthreads();
  }

  float* Cf = (float*)Cv;
  u16* Cb = (u16*)Cv;
#pragma unroll
  for (int i = 0; i < 4; i++)
#pragma unroll
    for (int j = 0; j < 4; j++) {
      const int row = m0 + wm + i * 16 + g * 4;
      const int col = n0 + wn + j * 16 + r;
#pragma unroll
      for (int q = 0; q < 4; q++) {
        float v = acc[i][j][q];
        if (F32OUT) Cf[(long)(row + q) * N + col] = v;
        else        Cb[(long)(row + q) * N + col] = f2bf(v);
      }
    }
}

// ---------------- RoPE in-place on Qlin & Klin ------------------------------
__global__ __launch_bounds__(256) void rope_kernel(u16* __restrict__ Q, u16* __restrict__ K,
                                                   const float* __restrict__ cosT,
                                                   const float* __restrict__ sinT) {
  int idx = blockIdx.x * 256 + threadIdx.x;  // bits: d:6 h:4 s:11 b:1
  int d = idx & 63;
  int h = (idx >> 6) & 15;
  int s = (idx >> 10) & 2047;
  int b = idx >> 21;
  float c = cosT[s * DH + d];
  float sn = sinT[s * DH + d];
  long base = ((long)(b * SEQ + s)) * DM + h * DH + d;
  float q1 = bf2f(Q[base]), q2 = bf2f(Q[base + 64]);
  Q[base]      = f2bf(q1 * c - q2 * sn);
  Q[base + 64] = f2bf(q2 * c + q1 * sn);
  float k1 = bf2f(K[base]), k2 = bf2f(K[base + 64]);
  K[base]      = f2bf(k1 * c - k2 * sn);
  K[base + 64] = f2bf(k2 * c + k1 * sn);
}

// ---------------- V transpose: Vlin[(b,s)][h*128+d] -> Vt[b,h,d,s] ---------
__global__ __launch_bounds__(256) void transpose_v(const u16* __restrict__ Vlin,
                                                   u16* __restrict__ Vt) {
  __shared__ u16 tile[64][129];
  int t = threadIdx.x;
  int st = blockIdx.x & 31;
  int h = (blockIdx.x >> 5) & 15;
  int b = blockIdx.x >> 9;
  int s0 = st * 64;
  const u16* src = Vlin + ((long)(b * SEQ + s0)) * DM + h * DH;
#pragma unroll
  for (int rr = 0; rr < 4; rr++) {
    int row = rr * 16 + (t >> 4);
    int col = (t & 15) * 8;
    s16x8 v = *(const s16x8*)&src[(long)row * DM + col];
#pragma unroll
    for (int j = 0; j < 8; j++) tile[row][col + j] = (u16)v[j];
  }
  __syncthreads();
  u16* dst = Vt + ((long)(b * NH + h)) * DH * SEQ + s0;
#pragma unroll
  for (int rr = 0; rr < 4; rr++) {
    int d = rr * 32 + (t >> 3);
    int sc = (t & 7) * 8;
    s16x8 o;
#pragma unroll
    for (int j = 0; j < 8; j++) o[j] = (short)tile[sc + j][d];
    *(s16x8*)&dst[(long)d * SEQ + sc] = o;
  }
}

// ---------------- Flash attention (causal) ---------------------------------
// grid: b*h*(S/64); 4 waves/block, each wave owns 16 q rows independently.
__global__ __launch_bounds__(256) void attn_kernel(const u16* __restrict__ Q,
                                                   const u16* __restrict__ K,
                                                   const u16* __restrict__ Vt,
                                                   u16* __restrict__ O) {
  __shared__ u16 Plds[4][16][32];
  const int tid = threadIdx.x, wave = tid >> 6, lane = tid & 63;
  const int r = lane & 15, g = lane >> 4;
  const int qt = blockIdx.x & 31;
  const int h = (blockIdx.x >> 5) & 15;
  const int b = blockIdx.x >> 9;
  const int q0 = qt * 64 + wave * 16;
  const float scale = 0.08838834764831845f;  // 1/sqrt(128)

  // Q fragments: 16 rows x 128 d  -> 4 K-chunks of 32
  s16x8 qf[4];
#pragma unroll
  for (int j = 0; j < 4; j++)
    qf[j] = *(const s16x8*)&Q[((long)(b * SEQ + q0 + r)) * DM + h * DH + j * 32 + g * 8];

  f32x4 oacc[8] = {};
  float mi[4] = {-1e30f, -1e30f, -1e30f, -1e30f};
  float li[4] = {0.f, 0.f, 0.f, 0.f};

  const u16* Kbh = K + (long)b * SEQ * DM + h * DH;
  const u16* Vbh = Vt + ((long)(b * NH + h)) * DH * SEQ;

  const int nk = ((q0 + 15) >> 5) + 1;
  for (int kt = 0; kt < nk; kt++) {
    const int k0 = kt * 32;
    const bool edge = (k0 + 31) > q0;
    f32x4 sacc[2] = {};
#pragma unroll
    for (int kk = 0; kk < 2; kk++)
#pragma unroll
      for (int j = 0; j < 4; j++) {
        s16x8 kf = *(const s16x8*)&Kbh[((long)(k0 + kk * 16 + r)) * DM + j * 32 + g * 8];
        sacc[kk] = __builtin_amdgcn_mfma_f32_16x16x32_bf16(qf[j], kf, sacc[kk], 0, 0, 0);
      }
    float alpha[4];
#pragma unroll
    for (int i = 0; i < 4; i++) {
      const int qrow = q0 + g * 4 + i;
      float s0 = sacc[0][i] * scale;
      float s1 = sacc[1][i] * scale;
      if (edge) {
        if (k0 + r > qrow) s0 = -1e30f;
        if (k0 + 16 + r > qrow) s1 = -1e30f;
      }
      float mx = fmaxf(s0, s1);
#pragma unroll
      for (int off = 1; off < 16; off <<= 1) mx = fmaxf(mx, __shfl_xor(mx, off, 64));
      const float mnew = fmaxf(mi[i], mx);
      float p0 = __expf(s0 - mnew);
      float p1 = __expf(s1 - mnew);
      if (edge) {
        if (k0 + r > qrow) p0 = 0.f;
        if (k0 + 16 + r > qrow) p1 = 0.f;
      }
      float a = __expf(mi[i] - mnew);
      float psum = p0 + p1;
#pragma unroll
      for (int off = 1; off < 16; off <<= 1) psum += __shfl_xor(psum, off, 64);
      li[i] = li[i] * a + psum;
      mi[i] = mnew;
      alpha[i] = a;
      Plds[wave][g * 4 + i][r] = f2bf(p0);
      Plds[wave][g * 4 + i][16 + r] = f2bf(p1);
    }
#pragma unroll
    for (int f = 0; f < 8; f++)
#pragma unroll
      for (int i = 0; i < 4; i++) oacc[f][i] *= alpha[i];
    s16x8 pfrag = *(const s16x8*)&Plds[wave][r][g * 8];
#pragma unroll
    for (int f = 0; f < 8; f++) {
      s16x8 vf = *(const s16x8*)&Vbh[((long)(f * 16 + r)) * SEQ + k0 + g * 8];
      oacc[f] = __builtin_amdgcn_mfma_f32_16x16x32_bf16(pfrag, vf, oacc[f], 0, 0, 0);
    }
  }
  float inv[4];
#pragma unroll
  for (int i = 0; i < 4; i++) inv[i] = 1.f / li[i];
#pragma unroll
  for (int f = 0; f < 8; f++)
#pragma unroll
    for (int i = 0; i < 4; i++) {
      O[((long)(b * SEQ + q0 + g * 4 + i)) * DM + h * DH + f * 16 + r] =
          f2bf(oacc[f][i] * inv[i]);
    }
}

// ---------------- launch ----------------------------------------------------
extern "C" void kernel_launch(void* const* d_in, const int* in_sizes, int n_in,
                              void* d_out, int out_size, void* d_ws, size_t ws_size,
                              hipStream_t stream) {
  const float* x    = (const float*)d_in[0];
  const float* Wq   = (const float*)d_in[1];
  const float* Wk   = (const float*)d_in[2];
  const float* Wv   = (const float*)d_in[3];
  const float* Wo   = (const float*)d_in[4];
  const float* cosT = (const float*)d_in[5];
  const float* sinT = (const float*)d_in[6];
  // d_in[7] = mask: causal, applied analytically.

  if (ws_size < (size_t)134217728) return;  // need 128 MB scratch

  char* ws = (char*)d_ws;
  u16* xb   = (u16*)(ws);
  u16* Wqb  = (u16*)(ws + 16777216);
  u16* Wkb  = (u16*)(ws + 25165824);
  u16* Wvb  = (u16*)(ws + 33554432);
  u16* Wob  = (u16*)(ws + 41943040);
  u16* Qlin = (u16*)(ws + 50331648);
  u16* Klin = (u16*)(ws + 67108864);
  u16* Vlin = (u16*)(ws + 83886080);
  u16* Vt   = (u16*)(ws + 100663296);
  u16* Olin = (u16*)(ws + 117440512);

  cast_kernel<<<8192, 256, 0, stream>>>(x, xb, 8388608 / 4);
  cast_kernel<<<4096, 256, 0, stream>>>(Wq, Wqb, 4194304 / 4);
  cast_kernel<<<4096, 256, 0, stream>>>(Wk, Wkb, 4194304 / 4);
  cast_kernel<<<4096, 256, 0, stream>>>(Wv, Wvb, 4194304 / 4);
  cast_kernel<<<4096, 256, 0, stream>>>(Wo, Wob, 4194304 / 4);

  dim3 ggrid(DM / 128, MROWS / 128);
  gemm_bt<false><<<ggrid, 256, 0, stream>>>(xb, Wqb, Qlin, MROWS, DM, DM);
  gemm_bt<false><<<ggrid, 256, 0, stream>>>(xb, Wkb, Klin, MROWS, DM, DM);
  gemm_bt<false><<<ggrid, 256, 0, stream>>>(xb, Wvb, Vlin, MROWS, DM, DM);

  rope_kernel<<<16384, 256, 0, stream>>>(Qlin, Klin, cosT, sinT);
  transpose_v<<<1024, 256, 0, stream>>>(Vlin, Vt);
  attn_kernel<<<1024, 256, 0, stream>>>(Qlin, Klin, Vt, Olin);

  gemm_bt<true><<<ggrid, 256, 0, stream>>>(Olin, Wob, d_out, MROWS, DM, DM);
}

// Round 2
// 511.437 us; speedup vs baseline: 1.4866x; 1.4866x over previous
//
#include <hip/hip_runtime.h>

typedef float f32x4 __attribute__((ext_vector_type(4)));
typedef short s16x8 __attribute__((ext_vector_type(8)));
typedef unsigned short u16;
typedef u16 u16x4 __attribute__((ext_vector_type(4)));

#define SEQ 2048
#define BATCH 2
#define NH 16
#define DH 128
#define DM 2048
#define MROWS (BATCH * SEQ)  // 4096

// 1/sqrt(128) * log2(e)  (softmax done in exp2 domain)
__device__ constexpr float SCALE2 = 0.12751879523531f;

__device__ __forceinline__ u16 f2bf(float f) {
  unsigned u = __float_as_uint(f);
  u += 0x7fffu + ((u >> 16) & 1u);
  return (u16)(u >> 16);
}
__device__ __forceinline__ float bf2f(u16 b) {
  return __uint_as_float(((unsigned)b) << 16);
}

__device__ __forceinline__ void gld_lds16(const void* g, void* l) {
  __builtin_amdgcn_global_load_lds(
      (const __attribute__((address_space(1))) unsigned int*)g,
      (__attribute__((address_space(3))) unsigned int*)l, 16, 0, 0);
}

// ---------------- cast f32 -> bf16 ----------------------------------------
__global__ __launch_bounds__(256) void cast_kernel(const float* __restrict__ in,
                                                   u16* __restrict__ out, int n4) {
  int i = blockIdx.x * 256 + threadIdx.x;
  if (i >= n4) return;
  float4 v = ((const float4*)in)[i];
  u16x4 o;
  o[0] = f2bf(v.x); o[1] = f2bf(v.y); o[2] = f2bf(v.z); o[3] = f2bf(v.w);
  ((u16x4*)out)[i] = o;
}

// ---------------- GEMM C[m][n] = sum_k A[m][k]*B[n][k]  (bt form) ----------
template <bool F32OUT>
__global__ __launch_bounds__(256) void gemm_bt(const u16* __restrict__ A,
                                               const u16* __restrict__ B,
                                               void* __restrict__ Cv,
                                               int M, int N, int K) {
  __shared__ u16 As[128 * 32];
  __shared__ u16 Bs[128 * 32];
  const int tid = threadIdx.x;
  const int wave = tid >> 6;
  const int lane = tid & 63;
  const int r = lane & 15, g = lane >> 4;

  const int m0 = blockIdx.y * 128;
  const int n0 = blockIdx.x * 128;
  const int wm = (wave >> 1) * 64;
  const int wn = (wave & 1) * 64;

  f32x4 acc[4][4] = {};

  const int row0 = tid >> 2;
  const int col0 = (tid & 3) * 8;
  const u16* ga0 = A + (long)(m0 + row0) * K + col0;
  const u16* ga1 = A + (long)(m0 + 64 + row0) * K + col0;
  const u16* gb0 = B + (long)(n0 + row0) * K + col0;
  const u16* gb1 = B + (long)(n0 + 64 + row0) * K + col0;

  u16* lA0 = &As[wave * 512];
  u16* lA1 = &As[2048 + wave * 512];
  u16* lB0 = &Bs[wave * 512];
  u16* lB1 = &Bs[2048 + wave * 512];

  for (int k0 = 0; k0 < K; k0 += 32) {
    gld_lds16(ga0 + k0, lA0);
    gld_lds16(ga1 + k0, lA1);
    gld_lds16(gb0 + k0, lB0);
    gld_lds16(gb1 + k0, lB1);
    __syncthreads();
    s16x8 af[4], bfr[4];
#pragma unroll
    for (int i = 0; i < 4; i++) {
      af[i]  = *(const s16x8*)&As[(wm + i * 16 + r) * 32 + g * 8];
      bfr[i] = *(const s16x8*)&Bs[(wn + i * 16 + r) * 32 + g * 8];
    }
#pragma unroll
    for (int i = 0; i < 4; i++)
#pragma unroll
      for (int j = 0; j < 4; j++)
        acc[i][j] = __builtin_amdgcn_mfma_f32_16x16x32_bf16(af[i], bfr[j], acc[i][j], 0, 0, 0);
    __syncthreads();
  }

  float* Cf = (float*)Cv;
  u16* Cb = (u16*)Cv;
#pragma unroll
  for (int i = 0; i < 4; i++)
#pragma unroll
    for (int j = 0; j < 4; j++) {
      const int row = m0 + wm + i * 16 + g * 4;
      const int col = n0 + wn + j * 16 + r;
#pragma unroll
      for (int q = 0; q < 4; q++) {
        float v = acc[i][j][q];
        if (F32OUT) Cf[(long)(row + q) * N + col] = v;
        else        Cb[(long)(row + q) * N + col] = f2bf(v);
      }
    }
}

// ---------------- RoPE in-place on Qlin & Klin ------------------------------
__global__ __launch_bounds__(256) void rope_kernel(u16* __restrict__ Q, u16* __restrict__ K,
                                                   const float* __restrict__ cosT,
                                                   const float* __restrict__ sinT) {
  int idx = blockIdx.x * 256 + threadIdx.x;  // bits: d:6 h:4 s:11 b:1
  int d = idx & 63;
  int h = (idx >> 6) & 15;
  int s = (idx >> 10) & 2047;
  int b = idx >> 21;
  float c = cosT[s * DH + d];
  float sn = sinT[s * DH + d];
  long base = ((long)(b * SEQ + s)) * DM + h * DH + d;
  float q1 = bf2f(Q[base]), q2 = bf2f(Q[base + 64]);
  Q[base]      = f2bf(q1 * c - q2 * sn);
  Q[base + 64] = f2bf(q2 * c + q1 * sn);
  float k1 = bf2f(K[base]), k2 = bf2f(K[base + 64]);
  K[base]      = f2bf(k1 * c - k2 * sn);
  K[base + 64] = f2bf(k2 * c + k1 * sn);
}

// ---------------- V transpose: Vlin[(b,s)][h*128+d] -> Vt[b,h,d,s] ---------
__global__ __launch_bounds__(256) void transpose_v(const u16* __restrict__ Vlin,
                                                   u16* __restrict__ Vt) {
  __shared__ u16 tile[64][129];
  int t = threadIdx.x;
  int st = blockIdx.x & 31;
  int h = (blockIdx.x >> 5) & 15;
  int b = blockIdx.x >> 9;
  int s0 = st * 64;
  const u16* src = Vlin + ((long)(b * SEQ + s0)) * DM + h * DH;
#pragma unroll
  for (int rr = 0; rr < 4; rr++) {
    int row = rr * 16 + (t >> 4);
    int col = (t & 15) * 8;
    s16x8 v = *(const s16x8*)&src[(long)row * DM + col];
#pragma unroll
    for (int j = 0; j < 8; j++) tile[row][col + j] = (u16)v[j];
  }
  __syncthreads();
  u16* dst = Vt + ((long)(b * NH + h)) * DH * SEQ + s0;
#pragma unroll
  for (int rr = 0; rr < 4; rr++) {
    int d = rr * 32 + (t >> 3);
    int sc = (t & 7) * 8;
    s16x8 o;
#pragma unroll
    for (int j = 0; j < 8; j++) o[j] = (short)tile[sc + j][d];
    *(s16x8*)&dst[(long)d * SEQ + sc] = o;
  }
}

// ---------------- Flash attention v2 ---------------------------------------
// Each wave owns a MIRROR PAIR of 16-row q-strips (qA low, qB high) so causal
// work per wave is constant. KVBLK=64. K/V fragment loads shared between
// strips. P buffer XOR-swizzled. exp2-domain online softmax.

__device__ __forceinline__ void softmax_update(
    f32x4 (&s)[4], float (&mi)[4], float (&li)[4], f32x4 (&oacc)[8],
    u16 (&pl)[16][64], int qbase, int k0, int r, int g) {
  const bool edge = (k0 + 63) > qbase;
  float alpha[4];
#pragma unroll
  for (int i = 0; i < 4; i++) {
    const int qrow = qbase + g * 4 + i;
    float v0 = s[0][i] * SCALE2;
    float v1 = s[1][i] * SCALE2;
    float v2 = s[2][i] * SCALE2;
    float v3 = s[3][i] * SCALE2;
    if (edge) {
      if (k0 +      r > qrow) v0 = -1e30f;
      if (k0 + 16 + r > qrow) v1 = -1e30f;
      if (k0 + 32 + r > qrow) v2 = -1e30f;
      if (k0 + 48 + r > qrow) v3 = -1e30f;
    }
    float mx = fmaxf(fmaxf(v0, v1), fmaxf(v2, v3));
#pragma unroll
    for (int off = 1; off < 16; off <<= 1) mx = fmaxf(mx, __shfl_xor(mx, off, 64));
    const float mnew = fmaxf(mi[i], mx);
    float p0 = exp2f(v0 - mnew);
    float p1 = exp2f(v1 - mnew);
    float p2 = exp2f(v2 - mnew);
    float p3 = exp2f(v3 - mnew);
    float a  = exp2f(mi[i] - mnew);
    float ps = (p0 + p1) + (p2 + p3);
#pragma unroll
    for (int off = 1; off < 16; off <<= 1) ps += __shfl_xor(ps, off, 64);
    li[i] = li[i] * a + ps;
    mi[i] = mnew;
    alpha[i] = a;
    const int row = g * 4 + i;
    const int sw = (row & 7) << 3;
    pl[row][(     r) ^ sw] = f2bf(p0);
    pl[row][(16 + r) ^ sw] = f2bf(p1);
    pl[row][(32 + r) ^ sw] = f2bf(p2);
    pl[row][(48 + r) ^ sw] = f2bf(p3);
  }
#pragma unroll
  for (int f = 0; f < 8; f++)
#pragma unroll
    for (int i = 0; i < 4; i++) oacc[f][i] *= alpha[i];
}

template <bool DOA>
__device__ __forceinline__ void attn_tile(
    int kt, int r, int g, int qA, int qB,
    const u16* __restrict__ Kbh, const u16* __restrict__ Vbh,
    const s16x8 (&qfA)[4], const s16x8 (&qfB)[4],
    f32x4 (&oaccA)[8], f32x4 (&oaccB)[8],
    float (&miA)[4], float (&liA)[4],
    float (&miB)[4], float (&liB)[4],
    u16 (&pl)[2][16][64]) {
  const long k0 = (long)kt * 64;
  f32x4 sA[4] = {};
  f32x4 sB[4] = {};
#pragma unroll
  for (int kk = 0; kk < 4; kk++) {
#pragma unroll
    for (int j = 0; j < 4; j++) {
      s16x8 kf = *(const s16x8*)&Kbh[(k0 + kk * 16 + r) * DM + j * 32 + g * 8];
      sB[kk] = __builtin_amdgcn_mfma_f32_16x16x32_bf16(qfB[j], kf, sB[kk], 0, 0, 0);
      if (DOA)
        sA[kk] = __builtin_amdgcn_mfma_f32_16x16x32_bf16(qfA[j], kf, sA[kk], 0, 0, 0);
    }
  }
  softmax_update(sB, miB, liB, oaccB, pl[1], qB, (int)k0, r, g);
  if (DOA) softmax_update(sA, miA, liA, oaccA, pl[0], qA, (int)k0, r, g);

  const int sw = (r & 7) << 3;
#pragma unroll
  for (int kc = 0; kc < 2; kc++) {
    s16x8 pfB = *(const s16x8*)&pl[1][r][(kc * 32 + g * 8) ^ sw];
    s16x8 pfA = {};
    if (DOA) pfA = *(const s16x8*)&pl[0][r][(kc * 32 + g * 8) ^ sw];
#pragma unroll
    for (int f = 0; f < 8; f++) {
      s16x8 vf = *(const s16x8*)&Vbh[(long)(f * 16 + r) * SEQ + k0 + kc * 32 + g * 8];
      oaccB[f] = __builtin_amdgcn_mfma_f32_16x16x32_bf16(pfB, vf, oaccB[f], 0, 0, 0);
      if (DOA)
        oaccA[f] = __builtin_amdgcn_mfma_f32_16x16x32_bf16(pfA, vf, oaccA[f], 0, 0, 0);
    }
  }
}

__global__ __launch_bounds__(256) void attn_kernel(const u16* __restrict__ Q,
                                                   const u16* __restrict__ K,
                                                   const u16* __restrict__ Vt,
                                                   u16* __restrict__ O) {
  __shared__ u16 Plds[4][2][16][64];
  const int tid = threadIdx.x, wave = tid >> 6, lane = tid & 63;
  const int r = lane & 15, g = lane >> 4;
  // bh fast-varying -> all 16 blocks of one (b,h) land on XCD bh%8 (L2 pin)
  const int bh = blockIdx.x & 31;
  const int jblk = blockIdx.x >> 5;  // 0..15
  const int h = bh & 15, b = bh >> 4;
  const int job = jblk * 4 + wave;   // 0..63
  const int qA = job * 16;
  const int qB = (127 - job) * 16;

  const u16* Qbh = Q + (long)b * SEQ * DM + h * DH;
  const u16* Kbh = K + (long)b * SEQ * DM + h * DH;
  const u16* Vbh = Vt + ((long)(b * NH + h)) * DH * SEQ;

  s16x8 qfA[4], qfB[4];
#pragma unroll
  for (int j = 0; j < 4; j++) {
    qfA[j] = *(const s16x8*)&Qbh[(long)(qA + r) * DM + j * 32 + g * 8];
    qfB[j] = *(const s16x8*)&Qbh[(long)(qB + r) * DM + j * 32 + g * 8];
  }

  f32x4 oaccA[8] = {};
  f32x4 oaccB[8] = {};
  float miA[4], liA[4], miB[4], liB[4];
#pragma unroll
  for (int i = 0; i < 4; i++) {
    miA[i] = -1e30f; liA[i] = 0.f;
    miB[i] = -1e30f; liB[i] = 0.f;
  }

  const int nkA = (qA + 15) / 64 + 1;
  const int nkB = (qB + 15) / 64 + 1;

  int kt = 0;
  for (; kt < nkA; ++kt)
    attn_tile<true>(kt, r, g, qA, qB, Kbh, Vbh, qfA, qfB,
                    oaccA, oaccB, miA, liA, miB, liB, Plds[wave]);

  // strip A complete: write it out, freeing pressure for the B-only loop
  {
    u16* Obh = O + (long)b * SEQ * DM + h * DH;
    float inv[4];
#pragma unroll
    for (int i = 0; i < 4; i++) inv[i] = 1.f / liA[i];
#pragma unroll
    for (int f = 0; f < 8; f++)
#pragma unroll
      for (int i = 0; i < 4; i++)
        Obh[(long)(qA + g * 4 + i) * DM + f * 16 + r] = f2bf(oaccA[f][i] * inv[i]);
  }

  for (; kt < nkB; ++kt)
    attn_tile<false>(kt, r, g, qA, qB, Kbh, Vbh, qfA, qfB,
                     oaccA, oaccB, miA, liA, miB, liB, Plds[wave]);

  {
    u16* Obh = O + (long)b * SEQ * DM + h * DH;
    float inv[4];
#pragma unroll
    for (int i = 0; i < 4; i++) inv[i] = 1.f / liB[i];
#pragma unroll
    for (int f = 0; f < 8; f++)
#pragma unroll
      for (int i = 0; i < 4; i++)
        Obh[(long)(qB + g * 4 + i) * DM + f * 16 + r] = f2bf(oaccB[f][i] * inv[i]);
  }
}

// ---------------- launch ----------------------------------------------------
extern "C" void kernel_launch(void* const* d_in, const int* in_sizes, int n_in,
                              void* d_out, int out_size, void* d_ws, size_t ws_size,
                              hipStream_t stream) {
  const float* x    = (const float*)d_in[0];
  const float* Wq   = (const float*)d_in[1];
  const float* Wk   = (const float*)d_in[2];
  const float* Wv   = (const float*)d_in[3];
  const float* Wo   = (const float*)d_in[4];
  const float* cosT = (const float*)d_in[5];
  const float* sinT = (const float*)d_in[6];
  // d_in[7] = mask: causal, applied analytically.

  if (ws_size < (size_t)134217728) return;  // need 128 MB scratch

  char* ws = (char*)d_ws;
  u16* xb   = (u16*)(ws);
  u16* Wqb  = (u16*)(ws + 16777216);
  u16* Wkb  = (u16*)(ws + 25165824);
  u16* Wvb  = (u16*)(ws + 33554432);
  u16* Wob  = (u16*)(ws + 41943040);
  u16* Qlin = (u16*)(ws + 50331648);
  u16* Klin = (u16*)(ws + 67108864);
  u16* Vlin = (u16*)(ws + 83886080);
  u16* Vt   = (u16*)(ws + 100663296);
  u16* Olin = (u16*)(ws + 117440512);

  cast_kernel<<<8192, 256, 0, stream>>>(x, xb, 8388608 / 4);
  cast_kernel<<<4096, 256, 0, stream>>>(Wq, Wqb, 4194304 / 4);
  cast_kernel<<<4096, 256, 0, stream>>>(Wk, Wkb, 4194304 / 4);
  cast_kernel<<<4096, 256, 0, stream>>>(Wv, Wvb, 4194304 / 4);
  cast_kernel<<<4096, 256, 0, stream>>>(Wo, Wob, 4194304 / 4);

  dim3 ggrid(DM / 128, MROWS / 128);
  gemm_bt<false><<<ggrid, 256, 0, stream>>>(xb, Wqb, Qlin, MROWS, DM, DM);
  gemm_bt<false><<<ggrid, 256, 0, stream>>>(xb, Wkb, Klin, MROWS, DM, DM);
  gemm_bt<false><<<ggrid, 256, 0, stream>>>(xb, Wvb, Vlin, MROWS, DM, DM);

  rope_kernel<<<16384, 256, 0, stream>>>(Qlin, Klin, cosT, sinT);
  transpose_v<<<1024, 256, 0, stream>>>(Vlin, Vt);
  attn_kernel<<<512, 256, 0, stream>>>(Qlin, Klin, Vt, Olin);

  gemm_bt<true><<<ggrid, 256, 0, stream>>>(Olin, Wob, d_out, MROWS, DM, DM);
}

// Round 3
// 470.962 us; speedup vs baseline: 1.6143x; 1.0859x over previous
//
#include <hip/hip_runtime.h>

typedef float f32x4 __attribute__((ext_vector_type(4)));
typedef short s16x8 __attribute__((ext_vector_type(8)));
typedef unsigned short u16;
typedef u16 u16x4 __attribute__((ext_vector_type(4)));

#define SEQ 2048
#define BATCH 2
#define NH 16
#define DH 128
#define DM 2048
#define MROWS (BATCH * SEQ)  // 4096

// 1/sqrt(128) * log2(e)  (softmax done in exp2 domain)
__device__ constexpr float SCALE2 = 0.12751879523531f;

__device__ __forceinline__ u16 f2bf(float f) {
  unsigned u = __float_as_uint(f);
  u += 0x7fffu + ((u >> 16) & 1u);
  return (u16)(u >> 16);
}
__device__ __forceinline__ float bf2f(u16 b) {
  return __uint_as_float(((unsigned)b) << 16);
}

__device__ __forceinline__ void gld_lds16(const void* g, void* l) {
  __builtin_amdgcn_global_load_lds(
      (const __attribute__((address_space(1))) unsigned int*)g,
      (__attribute__((address_space(3))) unsigned int*)l, 16, 0, 0);
}

// ---------------- cast f32 -> bf16 ----------------------------------------
__global__ __launch_bounds__(256) void cast_kernel(const float* __restrict__ in,
                                                   u16* __restrict__ out, int n4) {
  int i = blockIdx.x * 256 + threadIdx.x;
  if (i >= n4) return;
  float4 v = ((const float4*)in)[i];
  u16x4 o;
  o[0] = f2bf(v.x); o[1] = f2bf(v.y); o[2] = f2bf(v.z); o[3] = f2bf(v.w);
  ((u16x4*)out)[i] = o;
}

// ---------------- GEMM C[m][n] = sum_k A[m][k]*B[n][k]  (bt form) ----------
template <bool F32OUT>
__global__ __launch_bounds__(256) void gemm_bt(const u16* __restrict__ A,
                                               const u16* __restrict__ B,
                                               void* __restrict__ Cv,
                                               int M, int N, int K) {
  __shared__ u16 As[128 * 32];
  __shared__ u16 Bs[128 * 32];
  const int tid = threadIdx.x;
  const int wave = tid >> 6;
  const int lane = tid & 63;
  const int r = lane & 15, g = lane >> 4;

  const int m0 = blockIdx.y * 128;
  const int n0 = blockIdx.x * 128;
  const int wm = (wave >> 1) * 64;
  const int wn = (wave & 1) * 64;

  f32x4 acc[4][4] = {};

  const int row0 = tid >> 2;
  const int col0 = (tid & 3) * 8;
  const u16* ga0 = A + (long)(m0 + row0) * K + col0;
  const u16* ga1 = A + (long)(m0 + 64 + row0) * K + col0;
  const u16* gb0 = B + (long)(n0 + row0) * K + col0;
  const u16* gb1 = B + (long)(n0 + 64 + row0) * K + col0;

  u16* lA0 = &As[wave * 512];
  u16* lA1 = &As[2048 + wave * 512];
  u16* lB0 = &Bs[wave * 512];
  u16* lB1 = &Bs[2048 + wave * 512];

  for (int k0 = 0; k0 < K; k0 += 32) {
    gld_lds16(ga0 + k0, lA0);
    gld_lds16(ga1 + k0, lA1);
    gld_lds16(gb0 + k0, lB0);
    gld_lds16(gb1 + k0, lB1);
    __syncthreads();
    s16x8 af[4], bfr[4];
#pragma unroll
    for (int i = 0; i < 4; i++) {
      af[i]  = *(const s16x8*)&As[(wm + i * 16 + r) * 32 + g * 8];
      bfr[i] = *(const s16x8*)&Bs[(wn + i * 16 + r) * 32 + g * 8];
    }
#pragma unroll
    for (int i = 0; i < 4; i++)
#pragma unroll
      for (int j = 0; j < 4; j++)
        acc[i][j] = __builtin_amdgcn_mfma_f32_16x16x32_bf16(af[i], bfr[j], acc[i][j], 0, 0, 0);
    __syncthreads();
  }

  float* Cf = (float*)Cv;
  u16* Cb = (u16*)Cv;
#pragma unroll
  for (int i = 0; i < 4; i++)
#pragma unroll
    for (int j = 0; j < 4; j++) {
      const int row = m0 + wm + i * 16 + g * 4;
      const int col = n0 + wn + j * 16 + r;
#pragma unroll
      for (int q = 0; q < 4; q++) {
        float v = acc[i][j][q];
        if (F32OUT) Cf[(long)(row + q) * N + col] = v;
        else        Cb[(long)(row + q) * N + col] = f2bf(v);
      }
    }
}

// ---------------- RoPE in-place on Qlin & Klin ------------------------------
__global__ __launch_bounds__(256) void rope_kernel(u16* __restrict__ Q, u16* __restrict__ K,
                                                   const float* __restrict__ cosT,
                                                   const float* __restrict__ sinT) {
  int idx = blockIdx.x * 256 + threadIdx.x;  // bits: d:6 h:4 s:11 b:1
  int d = idx & 63;
  int h = (idx >> 6) & 15;
  int s = (idx >> 10) & 2047;
  int b = idx >> 21;
  float c = cosT[s * DH + d];
  float sn = sinT[s * DH + d];
  long base = ((long)(b * SEQ + s)) * DM + h * DH + d;
  float q1 = bf2f(Q[base]), q2 = bf2f(Q[base + 64]);
  Q[base]      = f2bf(q1 * c - q2 * sn);
  Q[base + 64] = f2bf(q2 * c + q1 * sn);
  float k1 = bf2f(K[base]), k2 = bf2f(K[base + 64]);
  K[base]      = f2bf(k1 * c - k2 * sn);
  K[base + 64] = f2bf(k2 * c + k1 * sn);
}

// ---------------- V transpose: Vlin[(b,s)][h*128+d] -> Vt[b,h,d,s] ---------
__global__ __launch_bounds__(256) void transpose_v(const u16* __restrict__ Vlin,
                                                   u16* __restrict__ Vt) {
  __shared__ u16 tile[64][129];
  int t = threadIdx.x;
  int st = blockIdx.x & 31;
  int h = (blockIdx.x >> 5) & 15;
  int b = blockIdx.x >> 9;
  int s0 = st * 64;
  const u16* src = Vlin + ((long)(b * SEQ + s0)) * DM + h * DH;
#pragma unroll
  for (int rr = 0; rr < 4; rr++) {
    int row = rr * 16 + (t >> 4);
    int col = (t & 15) * 8;
    s16x8 v = *(const s16x8*)&src[(long)row * DM + col];
#pragma unroll
    for (int j = 0; j < 8; j++) tile[row][col + j] = (u16)v[j];
  }
  __syncthreads();
  u16* dst = Vt + ((long)(b * NH + h)) * DH * SEQ + s0;
#pragma unroll
  for (int rr = 0; rr < 4; rr++) {
    int d = rr * 32 + (t >> 3);
    int sc = (t & 7) * 8;
    s16x8 o;
#pragma unroll
    for (int j = 0; j < 8; j++) o[j] = (short)tile[sc + j][d];
    *(s16x8*)&dst[(long)d * SEQ + sc] = o;
  }
}

// ---------------- Flash attention v3 ---------------------------------------
// Swapped QK^T: sacc = mfma(Kfrag, Qfrag) so lane (r,g) holds
// S[k = k0+kk*16+g*4+i][q = r]. Softmax row-reduce = in-register tree over
// 16 values + 2 shfl_xor (g axis) instead of 32 serial shuffles.
// mi/li are per-lane scalars. alpha / 1/li redistributed to the oacc layout
// (q = g*4+i) via a 16-float LDS bounce.

__device__ __forceinline__ void softmax_swapped(
    f32x4 (&s)[4], float& mi, float& li,
    u16 (&pl)[16][64], float (&als)[16],
    int qbase, int k0, int r, int g) {
  const int q = qbase + r;
  const bool edge = (k0 + 63) > qbase;
  float v[16];
#pragma unroll
  for (int kk = 0; kk < 4; kk++)
#pragma unroll
    for (int i = 0; i < 4; i++) {
      float x = s[kk][i] * SCALE2;
      if (edge && (k0 + kk * 16 + g * 4 + i > q)) x = -1e30f;
      v[kk * 4 + i] = x;
    }
  float t8[8], t4[4];
#pragma unroll
  for (int j = 0; j < 8; j++) t8[j] = fmaxf(v[2 * j], v[2 * j + 1]);
#pragma unroll
  for (int j = 0; j < 4; j++) t4[j] = fmaxf(t8[2 * j], t8[2 * j + 1]);
  float mx = fmaxf(fmaxf(t4[0], t4[1]), fmaxf(t4[2], t4[3]));
  mx = fmaxf(mx, __shfl_xor(mx, 16, 64));
  mx = fmaxf(mx, __shfl_xor(mx, 32, 64));
  const float mnew = fmaxf(mi, mx);
  const float a = exp2f(mi - mnew);
  float p[16];
#pragma unroll
  for (int j = 0; j < 16; j++) p[j] = exp2f(v[j] - mnew);
  float s8[8], s4[4];
#pragma unroll
  for (int j = 0; j < 8; j++) s8[j] = p[2 * j] + p[2 * j + 1];
#pragma unroll
  for (int j = 0; j < 4; j++) s4[j] = s8[2 * j] + s8[2 * j + 1];
  float ps = (s4[0] + s4[1]) + (s4[2] + s4[3]);
  ps += __shfl_xor(ps, 16, 64);
  ps += __shfl_xor(ps, 32, 64);
  li = li * a + ps;
  mi = mnew;
  const int sw = (r & 7) << 3;
#pragma unroll
  for (int kk = 0; kk < 4; kk++) {
    u16x4 w;
#pragma unroll
    for (int i = 0; i < 4; i++) w[i] = f2bf(p[kk * 4 + i]);
    *(u16x4*)&pl[r][(kk * 16 + g * 4) ^ sw] = w;
  }
  als[r] = a;  // all 4 g-lanes write the same value
}

template <bool DOA>
__device__ __forceinline__ void attn_tile(
    int kt, int r, int g, int qA, int qB,
    const u16* __restrict__ Kbh, const u16* __restrict__ Vbh,
    const s16x8 (&qfA)[4], const s16x8 (&qfB)[4],
    f32x4 (&oaccA)[8], f32x4 (&oaccB)[8],
    float& miA, float& liA, float& miB, float& liB,
    u16 (&pl)[2][16][64], float (&als)[2][16]) {
  const long k0 = (long)kt * 64;
  f32x4 sA[4] = {};
  f32x4 sB[4] = {};
#pragma unroll
  for (int kk = 0; kk < 4; kk++) {
#pragma unroll
    for (int j = 0; j < 4; j++) {
      s16x8 kf = *(const s16x8*)&Kbh[(k0 + kk * 16 + r) * DM + j * 32 + g * 8];
      // SWAPPED operands: K is the A-fragment, Q the B-fragment.
      sB[kk] = __builtin_amdgcn_mfma_f32_16x16x32_bf16(kf, qfB[j], sB[kk], 0, 0, 0);
      if (DOA)
        sA[kk] = __builtin_amdgcn_mfma_f32_16x16x32_bf16(kf, qfA[j], sA[kk], 0, 0, 0);
    }
  }
  softmax_swapped(sB, miB, liB, pl[1], als[1], qB, (int)k0, r, g);
  if (DOA) softmax_swapped(sA, miA, liA, pl[0], als[0], qA, (int)k0, r, g);

  // redistribute alpha to the oacc layout (q = g*4+i) and rescale
  f32x4 avB = *(const f32x4*)&als[1][g * 4];
#pragma unroll
  for (int f = 0; f < 8; f++)
#pragma unroll
    for (int i = 0; i < 4; i++) oaccB[f][i] *= avB[i];
  if (DOA) {
    f32x4 avA = *(const f32x4*)&als[0][g * 4];
#pragma unroll
    for (int f = 0; f < 8; f++)
#pragma unroll
      for (int i = 0; i < 4; i++) oaccA[f][i] *= avA[i];
  }

  const int sw = (r & 7) << 3;
#pragma unroll
  for (int kc = 0; kc < 2; kc++) {
    s16x8 pfB = *(const s16x8*)&pl[1][r][(kc * 32 + g * 8) ^ sw];
    s16x8 pfA = {};
    if (DOA) pfA = *(const s16x8*)&pl[0][r][(kc * 32 + g * 8) ^ sw];
#pragma unroll
    for (int f = 0; f < 8; f++) {
      s16x8 vf = *(const s16x8*)&Vbh[(long)(f * 16 + r) * SEQ + k0 + kc * 32 + g * 8];
      oaccB[f] = __builtin_amdgcn_mfma_f32_16x16x32_bf16(pfB, vf, oaccB[f], 0, 0, 0);
      if (DOA)
        oaccA[f] = __builtin_amdgcn_mfma_f32_16x16x32_bf16(pfA, vf, oaccA[f], 0, 0, 0);
    }
  }
}

__global__ __launch_bounds__(256) void attn_kernel(const u16* __restrict__ Q,
                                                   const u16* __restrict__ K,
                                                   const u16* __restrict__ Vt,
                                                   u16* __restrict__ O) {
  __shared__ u16 Plds[4][2][16][64];
  __shared__ float Alds[4][2][16];
  const int tid = threadIdx.x, wave = tid >> 6, lane = tid & 63;
  const int r = lane & 15, g = lane >> 4;
  // bh fast-varying -> all 16 blocks of one (b,h) land on XCD bh%8 (L2 pin)
  const int bh = blockIdx.x & 31;
  const int jblk = blockIdx.x >> 5;  // 0..15
  const int h = bh & 15, b = bh >> 4;
  const int job = jblk * 4 + wave;   // 0..63
  const int qA = job * 16;
  const int qB = (127 - job) * 16;

  const u16* Qbh = Q + (long)b * SEQ * DM + h * DH;
  const u16* Kbh = K + (long)b * SEQ * DM + h * DH;
  const u16* Vbh = Vt + ((long)(b * NH + h)) * DH * SEQ;

  s16x8 qfA[4], qfB[4];
#pragma unroll
  for (int j = 0; j < 4; j++) {
    qfA[j] = *(const s16x8*)&Qbh[(long)(qA + r) * DM + j * 32 + g * 8];
    qfB[j] = *(const s16x8*)&Qbh[(long)(qB + r) * DM + j * 32 + g * 8];
  }

  f32x4 oaccA[8] = {};
  f32x4 oaccB[8] = {};
  float miA = -1e30f, liA = 0.f, miB = -1e30f, liB = 0.f;

  const int nkA = (qA + 15) / 64 + 1;
  const int nkB = (qB + 15) / 64 + 1;

  int kt = 0;
  for (; kt < nkA; ++kt)
    attn_tile<true>(kt, r, g, qA, qB, Kbh, Vbh, qfA, qfB,
                    oaccA, oaccB, miA, liA, miB, liB, Plds[wave], Alds[wave]);

  // strip A complete: write it out (1/liA redistributed via LDS bounce)
  {
    Alds[wave][0][r] = 1.f / liA;
    f32x4 iv = *(const f32x4*)&Alds[wave][0][g * 4];
    u16* Obh = O + (long)b * SEQ * DM + h * DH;
#pragma unroll
    for (int f = 0; f < 8; f++)
#pragma unroll
      for (int i = 0; i < 4; i++)
        Obh[(long)(qA + g * 4 + i) * DM + f * 16 + r] = f2bf(oaccA[f][i] * iv[i]);
  }

  for (; kt < nkB; ++kt)
    attn_tile<false>(kt, r, g, qA, qB, Kbh, Vbh, qfA, qfB,
                     oaccA, oaccB, miA, liA, miB, liB, Plds[wave], Alds[wave]);

  {
    Alds[wave][1][r] = 1.f / liB;
    f32x4 iv = *(const f32x4*)&Alds[wave][1][g * 4];
    u16* Obh = O + (long)b * SEQ * DM + h * DH;
#pragma unroll
    for (int f = 0; f < 8; f++)
#pragma unroll
      for (int i = 0; i < 4; i++)
        Obh[(long)(qB + g * 4 + i) * DM + f * 16 + r] = f2bf(oaccB[f][i] * iv[i]);
  }
}

// ---------------- launch ----------------------------------------------------
extern "C" void kernel_launch(void* const* d_in, const int* in_sizes, int n_in,
                              void* d_out, int out_size, void* d_ws, size_t ws_size,
                              hipStream_t stream) {
  const float* x    = (const float*)d_in[0];
  const float* Wq   = (const float*)d_in[1];
  const float* Wk   = (const float*)d_in[2];
  const float* Wv   = (const float*)d_in[3];
  const float* Wo   = (const float*)d_in[4];
  const float* cosT = (const float*)d_in[5];
  const float* sinT = (const float*)d_in[6];
  // d_in[7] = mask: causal, applied analytically.

  if (ws_size < (size_t)134217728) return;  // need 128 MB scratch

  char* ws = (char*)d_ws;
  u16* xb   = (u16*)(ws);
  u16* Wqb  = (u16*)(ws + 16777216);
  u16* Wkb  = (u16*)(ws + 25165824);
  u16* Wvb  = (u16*)(ws + 33554432);
  u16* Wob  = (u16*)(ws + 41943040);
  u16* Qlin = (u16*)(ws + 50331648);
  u16* Klin = (u16*)(ws + 67108864);
  u16* Vlin = (u16*)(ws + 83886080);
  u16* Vt   = (u16*)(ws + 100663296);
  u16* Olin = (u16*)(ws + 117440512);

  cast_kernel<<<8192, 256, 0, stream>>>(x, xb, 8388608 / 4);
  cast_kernel<<<4096, 256, 0, stream>>>(Wq, Wqb, 4194304 / 4);
  cast_kernel<<<4096, 256, 0, stream>>>(Wk, Wkb, 4194304 / 4);
  cast_kernel<<<4096, 256, 0, stream>>>(Wv, Wvb, 4194304 / 4);
  cast_kernel<<<4096, 256, 0, stream>>>(Wo, Wob, 4194304 / 4);

  dim3 ggrid(DM / 128, MROWS / 128);
  gemm_bt<false><<<ggrid, 256, 0, stream>>>(xb, Wqb, Qlin, MROWS, DM, DM);
  gemm_bt<false><<<ggrid, 256, 0, stream>>>(xb, Wkb, Klin, MROWS, DM, DM);
  gemm_bt<false><<<ggrid, 256, 0, stream>>>(xb, Wvb, Vlin, MROWS, DM, DM);

  rope_kernel<<<16384, 256, 0, stream>>>(Qlin, Klin, cosT, sinT);
  transpose_v<<<1024, 256, 0, stream>>>(Vlin, Vt);
  attn_kernel<<<512, 256, 0, stream>>>(Qlin, Klin, Vt, Olin);

  gemm_bt<true><<<ggrid, 256, 0, stream>>>(Olin, Wob, d_out, MROWS, DM, DM);
}